// Round 1
// 14.067 us; speedup vs baseline: 1.0062x; 1.0062x over previous
//
#include <hip/hip_runtime.h>

// FastSpeech2 hard duration-based frame->token averaging.
// R9 = R8 (token-pull direct summation, 1 barrier, DPP wave scan) with:
//  (a) out-of-segment quad loads clamp-redirected to the lane's FIRST quad
//      (q0) instead of TF/4-1: the q0 line is already in L1 for this lane,
//      so wasted iterations no longer generate L2/HBM requests, while loads
//      stay straight-line (no exec-mask regions -> compiler still batches
//      all 9 loads for vmcnt pipelining). Unclamped positions mask the
//      duplicated values out exactly as before.
//  (b) 3-compare accumulate: accT over [si,ei) and acc0 over [si,mi);
//      acc1 = accT - acc0 (saves 1 VOPC/element in the hot loop).
// Output = [B*TT token_scalar | B duration_len(float)].

namespace {
constexpr int TT = 1024;   // tokens per row
constexpr int TF = 8192;   // frames per row
constexpr int NT = 512;    // threads per block (8 waves)
constexpr int NW = NT / 64;

// Canonical GCN wave64 inclusive add-scan via DPP (VALU pipe, no LDS).
__device__ __forceinline__ float wave_scan_incl(float x) {
    float f = x;
    {
        int t_ = __builtin_amdgcn_update_dpp(0, __float_as_int(f), 0x111, 0xf, 0xf, false);
        f += __int_as_float(t_);
    }
    {
        int t_ = __builtin_amdgcn_update_dpp(0, __float_as_int(f), 0x112, 0xf, 0xf, false);
        f += __int_as_float(t_);
    }
    {
        int t_ = __builtin_amdgcn_update_dpp(0, __float_as_int(f), 0x114, 0xf, 0xf, false);
        f += __int_as_float(t_);
    }
    {
        int t_ = __builtin_amdgcn_update_dpp(0, __float_as_int(f), 0x118, 0xf, 0xf, false);
        f += __int_as_float(t_);
    }
    {
        int t_ = __builtin_amdgcn_update_dpp(0, __float_as_int(f), 0x142, 0xa, 0xf, false);
        f += __int_as_float(t_);
    }
    {
        int t_ = __builtin_amdgcn_update_dpp(0, __float_as_int(f), 0x143, 0xc, 0xf, false);
        f += __int_as_float(t_);
    }
    return f;
}
}

__global__ __launch_bounds__(NT, 8) void fs2_avg_kernel(
    const float* __restrict__ frame_scalar,
    const float* __restrict__ duration,
    const int* __restrict__ frame_scalar_len,
    const int* __restrict__ duration_len,
    float* __restrict__ out,
    int n_rows)
{
    __shared__ alignas(16) float s_wA[NW];

    const int b = blockIdx.x;
    const int t = threadIdx.x;
    const int lane = t & 63;
    const int wid = t >> 6;

    const int dlen = duration_len[b];
    const float flen = (float)frame_scalar_len[b];

    const float* frow = frame_scalar + (size_t)b * TF;

    // Output 1: duration_len passthrough (independent; issue early)
    if (t == 0) out[(size_t)n_rows * TT + b] = (float)dlen;

    // ---- duration load (predicated) + round/clamp/mask ----
    const int j0 = t * 2;
    float2 d2 = (j0 < dlen)
        ? *reinterpret_cast<const float2*>(duration + (size_t)b * TT + j0)
        : make_float2(0.f, 0.f);
    float d0 = fmaxf(rintf(d2.x), 0.0f); if (j0 + 0 >= dlen) d0 = 0.0f;
    float d1 = fmaxf(rintf(d2.y), 0.0f); if (j0 + 1 >= dlen) d1 = 0.0f;
    const float c0 = d0, c1 = c0 + d1;

    // ---- wave64 inclusive scan of per-thread duration sums (DPP, exact ints) ----
    const float ws = wave_scan_incl(c1);
    if (lane == 63) s_wA[wid] = ws;

    __syncthreads();   // the only barrier: wave totals visible

    // ---- cross-wave base: two broadcast float4 reads + predicated adds ----
    const float4 wA0 = *reinterpret_cast<const float4*>(&s_wA[0]);
    const float4 wA1 = *reinterpret_cast<const float4*>(&s_wA[4]);
    float base = ws - c1;   // exclusive prefix within wave
    base += (wid > 0) ? wA0.x : 0.f;
    base += (wid > 1) ? wA0.y : 0.f;
    base += (wid > 2) ? wA0.z : 0.f;
    base += (wid > 3) ? wA0.w : 0.f;
    base += (wid > 4) ? wA1.x : 0.f;
    base += (wid > 5) ? wA1.y : 0.f;
    base += (wid > 6) ? wA1.z : 0.f;

    // ---- clipped token boundaries (integers in fp32, exact) ----
    const float sprev0 = (j0 == 0) ? 0.0f : fminf(base, flen);
    const float e0 = fminf(base + c0, flen);
    const float e1 = fminf(base + c1, flen);

    const int si = (int)sprev0;
    const int mi = (int)e0;
    const int ei = (int)e1;

    // ---- direct masked summation over <=9 aligned quads ----
    // Out-of-segment quads redirect to q0 (same-lane L1-hot line): no L2
    // traffic for wasted iterations; unclamped positions mask them out.
    float acc0 = 0.0f, accT = 0.0f;
    if (ei > si) {
        const int q0 = si >> 2;
        #pragma unroll
        for (int j = 0; j < 9; ++j) {
            const int q  = q0 + j;                  // logical quad (for positions)
            const int p0 = 4 * q;                   // UNCLAMPED positions
            const int qc = (p0 < ei) ? q : q0;      // clamped for load (L1-hot)
            const float4 v = *reinterpret_cast<const float4*>(frow + 4 * qc);
            {
                const int p = p0 + 0; const float x = v.x;
                const bool inT = (p >= si) & (p < ei);
                accT += inT ? x : 0.f;
                acc0 += (inT & (p < mi)) ? x : 0.f;
            }
            {
                const int p = p0 + 1; const float x = v.y;
                const bool inT = (p >= si) & (p < ei);
                accT += inT ? x : 0.f;
                acc0 += (inT & (p < mi)) ? x : 0.f;
            }
            {
                const int p = p0 + 2; const float x = v.z;
                const bool inT = (p >= si) & (p < ei);
                accT += inT ? x : 0.f;
                acc0 += (inT & (p < mi)) ? x : 0.f;
            }
            {
                const int p = p0 + 3; const float x = v.w;
                const bool inT = (p >= si) & (p < ei);
                accT += inT ? x : 0.f;
                acc0 += (inT & (p < mi)) ? x : 0.f;
            }
        }
    }
    const float acc1 = accT - acc0;

    const float o0 = (mi > si) ? acc0 / (e0 - sprev0) : 0.0f;
    const float o1 = (ei > mi) ? acc1 / (e1 - e0) : 0.0f;

    *reinterpret_cast<float2*>(out + (size_t)b * TT + j0) = make_float2(o0, o1);
}

extern "C" void kernel_launch(void* const* d_in, const int* in_sizes, int n_in,
                              void* d_out, int out_size, void* d_ws, size_t ws_size,
                              hipStream_t stream) {
    const float* frame_scalar     = (const float*)d_in[0];
    const float* duration         = (const float*)d_in[1];
    const int*   frame_scalar_len = (const int*)d_in[2];
    const int*   duration_len     = (const int*)d_in[3];
    float* out = (float*)d_out;
    const int B = in_sizes[2];   // frame_scalar_len has B elements
    fs2_avg_kernel<<<B, NT, 0, stream>>>(frame_scalar, duration, frame_scalar_len,
                                         duration_len, out, B);
}